// Round 17
// baseline (26.900 us; speedup 1.0000x reference)
//
#include <hip/hip_runtime.h>
#include <math.h>

#define GAMMA 0.999f
#define LAM   0.95f
#define GL    (GAMMA * LAM)

constexpr int T    = 4096;
constexpr int NENV = 1024;

// Segment summary: adv entering from later time is x.
//   transfer: adv_out = P + Q*x
//   sum adv^2      = s2 + 2*spq*x + sq2*x^2
//   sum logp*adv   = slpp + slpq*x
struct Seg { float P, Q, s2, spq, sq2, slpp, slpq; };

// A = earlier-time (outer), B = later-time (inner, applied first).
__device__ __forceinline__ Seg seg_combine(const Seg& A, const Seg& B) {
    Seg r;
    const float qb = B.Q, pb = B.P;
    r.s2   = B.s2 + A.s2 + 2.f * A.spq * pb + A.sq2 * pb * pb;
    r.spq  = B.spq + (A.spq + A.sq2 * pb) * qb;
    r.sq2  = B.sq2 + A.sq2 * qb * qb;
    r.slpp = B.slpp + A.slpp + A.slpq * pb;
    r.slpq = B.slpq + A.slpq * qb;
    r.P    = A.P + A.Q * pb;
    r.Q    = A.Q * qb;
    return r;
}

// Pass 1: backward scan per (chunk, env-pair). Grid = 2*C blocks x 256 thr.
// Summary layout [c][env][8]: a block's stores are CONTIGUOUS (coalesced).
// unroll 8 widens the load-use window (~2x loads in flight vs unroll 4).
__global__ __launch_bounds__(256) void gae_pass1(
    const float* __restrict__ R, const float* __restrict__ LP,
    const float* __restrict__ V, const float* __restrict__ LV,
    const float* __restrict__ E, const float* __restrict__ M,
    float* __restrict__ summ, float* __restrict__ entp, int C, int L)
{
    const int c    = blockIdx.x >> 1;
    const int env  = 2 * ((blockIdx.x & 1) * 256 + threadIdx.x);  // even
    const int t_lo = c * L;
    const int t_hi = t_lo + L - 1;

    float2 vn = (c == C - 1) ? *(const float2*)(LV + env)
                             : *(const float2*)(V + (size_t)(t_hi + 1) * NENV + env);

    float p0=0.f,q0=1.f,s20=0.f,spq0=0.f,sq20=0.f,slpp0=0.f,slpq0=0.f;
    float p1=0.f,q1=1.f,s21=0.f,spq1=0.f,sq21=0.f,slpp1=0.f,slpq1=0.f;
    float sent = 0.f;

    #pragma unroll 8
    for (int t = t_hi; t >= t_lo; --t) {
        const size_t idx = (size_t)t * NENV + env;
        const float2 r  = *(const float2*)(R  + idx);
        const float2 v  = *(const float2*)(V  + idx);
        const float2 m  = *(const float2*)(M  + idx);
        const float2 lp = *(const float2*)(LP + idx);
        const float2 e  = *(const float2*)(E  + idx);

        float ret = fmaf(GAMMA * vn.x, m.x, r.x);
        float a   = ret - v.x;
        float b   = GL * m.x;
        p0 = fmaf(b, p0, a); q0 = b * q0;
        s20 = fmaf(p0, p0, s20); spq0 = fmaf(p0, q0, spq0); sq20 = fmaf(q0, q0, sq20);
        slpp0 = fmaf(lp.x, p0, slpp0); slpq0 = fmaf(lp.x, q0, slpq0);

        ret = fmaf(GAMMA * vn.y, m.y, r.y);
        a   = ret - v.y;
        b   = GL * m.y;
        p1 = fmaf(b, p1, a); q1 = b * q1;
        s21 = fmaf(p1, p1, s21); spq1 = fmaf(p1, q1, spq1); sq21 = fmaf(q1, q1, sq21);
        slpp1 = fmaf(lp.y, p1, slpp1); slpq1 = fmaf(lp.y, q1, slpq1);

        sent += e.x + e.y;
        vn = v;
    }

    // [c][env][8]: this thread's 64B is contiguous; block covers 16KB.
    float4* s0 = (float4*)(summ + ((size_t)c * NENV + env) * 8);
    s0[0] = make_float4(p0, q0, s20, spq0);
    s0[1] = make_float4(sq20, slpp0, slpq0, 0.f);
    s0[2] = make_float4(p1, q1, s21, spq1);
    s0[3] = make_float4(sq21, slpp1, slpq1, 0.f);

    #pragma unroll
    for (int o = 32; o > 0; o >>= 1) sent += __shfl_down(sent, o, 64);
    __shared__ float ls[4];
    const int lane = threadIdx.x & 63, w = threadIdx.x >> 6;
    if (lane == 0) ls[w] = sent;
    __syncthreads();
    if (threadIdx.x == 0) entp[blockIdx.x] = (ls[0] + ls[1]) + (ls[2] + ls[3]);
}

// Pass 2: one wave per env; ordered tree-reduce of the chunk monoid.
// Lane l holds chunks [C-(l+1)K, C-lK): lane 0 = latest time (innermost).
__global__ __launch_bounds__(256) void gae_pass2(
    const float* __restrict__ summ, float* __restrict__ part, int C)
{
    const int lane = threadIdx.x & 63;
    const int env  = blockIdx.x * 4 + (threadIdx.x >> 6);
    const int K    = C >> 6;
    const int c_hi = C - 1 - lane * K;

    const float* base = summ + ((size_t)c_hi * NENV + env) * 8;
    float4 a0 = ((const float4*)base)[0];
    float4 a1 = ((const float4*)base)[1];
    Seg cur = { a0.x, a0.y, a0.z, a0.w, a1.x, a1.y, a1.z };

    for (int j = 1; j < K; ++j) {
        const float* b = summ + ((size_t)(c_hi - j) * NENV + env) * 8;
        float4 b0 = ((const float4*)b)[0];
        float4 b1 = ((const float4*)b)[1];
        Seg A = { b0.x, b0.y, b0.z, b0.w, b1.x, b1.y, b1.z };
        cur = seg_combine(A, cur);   // A is earlier time
    }

    #pragma unroll
    for (int d = 1; d < 64; d <<= 1) {
        Seg o;
        o.P    = __shfl_down(cur.P,    d, 64);
        o.Q    = __shfl_down(cur.Q,    d, 64);
        o.s2   = __shfl_down(cur.s2,   d, 64);
        o.spq  = __shfl_down(cur.spq,  d, 64);
        o.sq2  = __shfl_down(cur.sq2,  d, 64);
        o.slpp = __shfl_down(cur.slpp, d, 64);
        o.slpq = __shfl_down(cur.slpq, d, 64);
        cur = seg_combine(o, cur);   // higher lane = earlier time = outer
    }

    if (lane == 0) {   // x = 0 at the latest timestep
        part[env * 2 + 0] = cur.s2;
        part[env * 2 + 1] = cur.slpp;
    }
}

// Pass 3: final scalar reduction.
__global__ __launch_bounds__(256) void gae_pass3(
    const float* __restrict__ part, const float* __restrict__ entp,
    int nent, float* __restrict__ out)
{
    const int tid = threadIdx.x;
    float crit = 0.f, act = 0.f, ent = 0.f;
    for (int i = tid; i < NENV; i += 256) {
        crit += part[2 * i + 0];
        act  += part[2 * i + 1];
    }
    for (int i = tid; i < nent; i += 256) ent += entp[i];

    #pragma unroll
    for (int o = 32; o > 0; o >>= 1) {
        crit += __shfl_down(crit, o, 64);
        act  += __shfl_down(act,  o, 64);
        ent  += __shfl_down(ent,  o, 64);
    }
    __shared__ float lc[4], la[4], le[4];
    const int lane = tid & 63, w = tid >> 6;
    if (lane == 0) { lc[w] = crit; la[w] = act; le[w] = ent; }
    __syncthreads();
    if (tid == 0) {
        crit = (lc[0] + lc[1]) + (lc[2] + lc[3]);
        act  = (la[0] + la[1]) + (la[2] + la[3]);
        ent  = (le[0] + le[1]) + (le[2] + le[3]);
        const float inv = 1.f / (float)((size_t)T * NENV);
        out[0] = crit * inv;
        out[1] = -act * inv - 0.01f * (ent * inv);
    }
}

extern "C" void kernel_launch(void* const* d_in, const int* in_sizes, int n_in,
                              void* d_out, int out_size, void* d_ws, size_t ws_size,
                              hipStream_t stream) {
    const float* R  = (const float*)d_in[0];
    const float* LP = (const float*)d_in[1];
    const float* V  = (const float*)d_in[2];
    const float* LV = (const float*)d_in[3];
    const float* E  = (const float*)d_in[4];
    const float* M  = (const float*)d_in[5];
    float* out = (float*)d_out;

    // C chunks (multiple of 64, power of two); fit workspace.
    int C = 256;
    while (C > 64) {
        size_t need = ((size_t)C * 8 * NENV + (size_t)C * 2 + 2 * NENV) * sizeof(float);
        if (need <= ws_size) break;
        C >>= 1;
    }
    const int L = T / C;

    float* summ = (float*)d_ws;                      // C*8*NENV  ([c][env][8])
    float* entp = summ + (size_t)C * 8 * NENV;       // 2*C
    float* part = entp + (size_t)C * 2;              // 2*NENV

    gae_pass1<<<C * 2, 256, 0, stream>>>(R, LP, V, LV, E, M, summ, entp, C, L);
    gae_pass2<<<NENV / 4, 256, 0, stream>>>(summ, part, C);
    gae_pass3<<<1, 256, 0, stream>>>(part, entp, C * 2, out);
}

// Round 18
// 25.693 us; speedup vs baseline: 1.0470x; 1.0470x over previous
//
#include <hip/hip_runtime.h>
#include <math.h>

#define GAMMA 0.999f
#define LAM   0.95f
#define GL    (GAMMA * LAM)

constexpr int T    = 4096;
constexpr int NENV = 1024;

// Segment summary: adv entering from later time is x.
//   transfer: adv_out = P + Q*x
//   sum adv^2      = s2 + 2*spq*x + sq2*x^2
//   sum logp*adv   = slpp + slpq*x
struct Seg { float P, Q, s2, spq, sq2, slpp, slpq; };

// A = earlier-time (outer), B = later-time (inner, applied first).
__device__ __forceinline__ Seg seg_combine(const Seg& A, const Seg& B) {
    Seg r;
    const float qb = B.Q, pb = B.P;
    r.s2   = B.s2 + A.s2 + 2.f * A.spq * pb + A.sq2 * pb * pb;
    r.spq  = B.spq + (A.spq + A.sq2 * pb) * qb;
    r.sq2  = B.sq2 + A.sq2 * qb * qb;
    r.slpp = B.slpp + A.slpp + A.slpq * pb;
    r.slpq = B.slpq + A.slpq * qb;
    r.P    = A.P + A.Q * pb;
    r.Q    = A.Q * qb;
    return r;
}

// Pass 1: backward scan per (chunk, env-pair). Grid = 2*C blocks x 256 thr.
// Summary layout [c][env][8]: a block's stores are CONTIGUOUS (coalesced);
// the scatter moves to pass2's small, massively-parallel read side.
__global__ __launch_bounds__(256) void gae_pass1(
    const float* __restrict__ R, const float* __restrict__ LP,
    const float* __restrict__ V, const float* __restrict__ LV,
    const float* __restrict__ E, const float* __restrict__ M,
    float* __restrict__ summ, float* __restrict__ entp, int C, int L)
{
    const int c    = blockIdx.x >> 1;
    const int env  = 2 * ((blockIdx.x & 1) * 256 + threadIdx.x);  // even
    const int t_lo = c * L;
    const int t_hi = t_lo + L - 1;

    float2 vn = (c == C - 1) ? *(const float2*)(LV + env)
                             : *(const float2*)(V + (size_t)(t_hi + 1) * NENV + env);

    float p0=0.f,q0=1.f,s20=0.f,spq0=0.f,sq20=0.f,slpp0=0.f,slpq0=0.f;
    float p1=0.f,q1=1.f,s21=0.f,spq1=0.f,sq21=0.f,slpp1=0.f,slpq1=0.f;
    float sent = 0.f;

    #pragma unroll 4
    for (int t = t_hi; t >= t_lo; --t) {
        const size_t idx = (size_t)t * NENV + env;
        const float2 r  = *(const float2*)(R  + idx);
        const float2 v  = *(const float2*)(V  + idx);
        const float2 m  = *(const float2*)(M  + idx);
        const float2 lp = *(const float2*)(LP + idx);
        const float2 e  = *(const float2*)(E  + idx);

        float ret = fmaf(GAMMA * vn.x, m.x, r.x);
        float a   = ret - v.x;
        float b   = GL * m.x;
        p0 = fmaf(b, p0, a); q0 = b * q0;
        s20 = fmaf(p0, p0, s20); spq0 = fmaf(p0, q0, spq0); sq20 = fmaf(q0, q0, sq20);
        slpp0 = fmaf(lp.x, p0, slpp0); slpq0 = fmaf(lp.x, q0, slpq0);

        ret = fmaf(GAMMA * vn.y, m.y, r.y);
        a   = ret - v.y;
        b   = GL * m.y;
        p1 = fmaf(b, p1, a); q1 = b * q1;
        s21 = fmaf(p1, p1, s21); spq1 = fmaf(p1, q1, spq1); sq21 = fmaf(q1, q1, sq21);
        slpp1 = fmaf(lp.y, p1, slpp1); slpq1 = fmaf(lp.y, q1, slpq1);

        sent += e.x + e.y;
        vn = v;
    }

    // [c][env][8]: this thread's 64B is contiguous; block covers 16KB.
    float4* s0 = (float4*)(summ + ((size_t)c * NENV + env) * 8);
    s0[0] = make_float4(p0, q0, s20, spq0);
    s0[1] = make_float4(sq20, slpp0, slpq0, 0.f);
    s0[2] = make_float4(p1, q1, s21, spq1);
    s0[3] = make_float4(sq21, slpp1, slpq1, 0.f);

    #pragma unroll
    for (int o = 32; o > 0; o >>= 1) sent += __shfl_down(sent, o, 64);
    __shared__ float ls[4];
    const int lane = threadIdx.x & 63, w = threadIdx.x >> 6;
    if (lane == 0) ls[w] = sent;
    __syncthreads();
    if (threadIdx.x == 0) entp[blockIdx.x] = (ls[0] + ls[1]) + (ls[2] + ls[3]);
}

// Pass 2: one wave per env; ordered tree-reduce of the chunk monoid.
// Lane l holds chunks [C-(l+1)K, C-lK): lane 0 = latest time (innermost).
__global__ __launch_bounds__(256) void gae_pass2(
    const float* __restrict__ summ, float* __restrict__ part, int C)
{
    const int lane = threadIdx.x & 63;
    const int env  = blockIdx.x * 4 + (threadIdx.x >> 6);
    const int K    = C >> 6;
    const int c_hi = C - 1 - lane * K;

    const float* base = summ + ((size_t)c_hi * NENV + env) * 8;
    float4 a0 = ((const float4*)base)[0];
    float4 a1 = ((const float4*)base)[1];
    Seg cur = { a0.x, a0.y, a0.z, a0.w, a1.x, a1.y, a1.z };

    for (int j = 1; j < K; ++j) {
        const float* b = summ + ((size_t)(c_hi - j) * NENV + env) * 8;
        float4 b0 = ((const float4*)b)[0];
        float4 b1 = ((const float4*)b)[1];
        Seg A = { b0.x, b0.y, b0.z, b0.w, b1.x, b1.y, b1.z };
        cur = seg_combine(A, cur);   // A is earlier time
    }

    #pragma unroll
    for (int d = 1; d < 64; d <<= 1) {
        Seg o;
        o.P    = __shfl_down(cur.P,    d, 64);
        o.Q    = __shfl_down(cur.Q,    d, 64);
        o.s2   = __shfl_down(cur.s2,   d, 64);
        o.spq  = __shfl_down(cur.spq,  d, 64);
        o.sq2  = __shfl_down(cur.sq2,  d, 64);
        o.slpp = __shfl_down(cur.slpp, d, 64);
        o.slpq = __shfl_down(cur.slpq, d, 64);
        cur = seg_combine(o, cur);   // higher lane = earlier time = outer
    }

    if (lane == 0) {   // x = 0 at the latest timestep
        part[env * 2 + 0] = cur.s2;
        part[env * 2 + 1] = cur.slpp;
    }
}

// Pass 3: final scalar reduction.
__global__ __launch_bounds__(256) void gae_pass3(
    const float* __restrict__ part, const float* __restrict__ entp,
    int nent, float* __restrict__ out)
{
    const int tid = threadIdx.x;
    float crit = 0.f, act = 0.f, ent = 0.f;
    for (int i = tid; i < NENV; i += 256) {
        crit += part[2 * i + 0];
        act  += part[2 * i + 1];
    }
    for (int i = tid; i < nent; i += 256) ent += entp[i];

    #pragma unroll
    for (int o = 32; o > 0; o >>= 1) {
        crit += __shfl_down(crit, o, 64);
        act  += __shfl_down(act,  o, 64);
        ent  += __shfl_down(ent,  o, 64);
    }
    __shared__ float lc[4], la[4], le[4];
    const int lane = tid & 63, w = tid >> 6;
    if (lane == 0) { lc[w] = crit; la[w] = act; le[w] = ent; }
    __syncthreads();
    if (tid == 0) {
        crit = (lc[0] + lc[1]) + (lc[2] + lc[3]);
        act  = (la[0] + la[1]) + (la[2] + la[3]);
        ent  = (le[0] + le[1]) + (le[2] + le[3]);
        const float inv = 1.f / (float)((size_t)T * NENV);
        out[0] = crit * inv;
        out[1] = -act * inv - 0.01f * (ent * inv);
    }
}

extern "C" void kernel_launch(void* const* d_in, const int* in_sizes, int n_in,
                              void* d_out, int out_size, void* d_ws, size_t ws_size,
                              hipStream_t stream) {
    const float* R  = (const float*)d_in[0];
    const float* LP = (const float*)d_in[1];
    const float* V  = (const float*)d_in[2];
    const float* LV = (const float*)d_in[3];
    const float* E  = (const float*)d_in[4];
    const float* M  = (const float*)d_in[5];
    float* out = (float*)d_out;

    // C chunks (multiple of 64, power of two); fit workspace.
    int C = 256;
    while (C > 64) {
        size_t need = ((size_t)C * 8 * NENV + (size_t)C * 2 + 2 * NENV) * sizeof(float);
        if (need <= ws_size) break;
        C >>= 1;
    }
    const int L = T / C;

    float* summ = (float*)d_ws;                      // C*8*NENV  ([c][env][8])
    float* entp = summ + (size_t)C * 8 * NENV;       // 2*C
    float* part = entp + (size_t)C * 2;              // 2*NENV

    gae_pass1<<<C * 2, 256, 0, stream>>>(R, LP, V, LV, E, M, summ, entp, C, L);
    gae_pass2<<<NENV / 4, 256, 0, stream>>>(summ, part, C);
    gae_pass3<<<1, 256, 0, stream>>>(part, entp, C * 2, out);
}